// Round 6
// baseline (105.383 us; speedup 1.0000x reference)
//
#include <hip/hip_runtime.h>
#include <hip/hip_bf16.h>
#include <math.h>

// Problem constants
#define HIDDEN 512
#define NHEADS 16
#define HDIM   32
#define BATCH  2
#define SEQ    1024
#define MROWS  (BATCH * SEQ)   // 2048

constexpr float LOG2_GAMMA = -0.15200309344504997f; // log2(0.9)

typedef __hip_bfloat16 bf16;
typedef __attribute__((ext_vector_type(8))) short short8;
typedef __attribute__((ext_vector_type(4))) float f32x4;

__device__ __forceinline__ void async16(const void* g, void* l) {
    __builtin_amdgcn_global_load_lds(
        (const __attribute__((address_space(1))) void*)g,
        (__attribute__((address_space(3))) void*)l, 16, 0, 0);
}

__device__ __forceinline__ unsigned short f2bf_bits(float f) {
    bf16 b = __float2bfloat16(f);
    return *(unsigned short*)&b;
}

// ---------------------------------------------------------------------------
// Weight prep only (x-cast is folded into the QKV GEMM): transpose+cast the
// 4 weights fp32 [512 k][512 n] -> bf16 [n][512 k].
// ---------------------------------------------------------------------------
__global__ __launch_bounds__(256) void prep_w(
    const float* __restrict__ qw, const float* __restrict__ kw,
    const float* __restrict__ vw, const float* __restrict__ ow,
    bf16* __restrict__ wqkvt, bf16* __restrict__ wot)
{
    const int blk = blockIdx.x, tid = threadIdx.x;
    const int widx = blk >> 6;
    const int tile = blk & 63;
    const int tk = (tile & 7) * 64, tn = (tile >> 3) * 64;
    const float* w = widx == 0 ? qw : widx == 1 ? kw : widx == 2 ? vw : ow;
    __shared__ float t[64][65];
    #pragma unroll
    for (int u = 0; u < 4; ++u) {
        const int r = u * 16 + (tid >> 4);
        const int c = (tid & 15) * 4;
        float4 v = *(const float4*)&w[(size_t)(tk + r) * 512 + tn + c];
        t[r][c + 0] = v.x; t[r][c + 1] = v.y; t[r][c + 2] = v.z; t[r][c + 3] = v.w;
    }
    __syncthreads();
    #pragma unroll
    for (int u = 0; u < 2; ++u) {
        const int rr = u * 32 + (tid >> 3);
        const int cc = (tid & 7) * 8;
        alignas(16) unsigned short tmp[8];
        #pragma unroll
        for (int i = 0; i < 8; ++i) tmp[i] = f2bf_bits(t[cc + i][rr]);
        bf16* dst = (widx < 3)
            ? &wqkvt[((size_t)widx * 512 + tn + rr) * 512 + tk + cc]
            : &wot[(size_t)(tn + rr) * 512 + tk + cc];
        *(short8*)dst = *(short8*)tmp;
    }
}

// ---------------------------------------------------------------------------
// Persistent-B MFMA GEMM: block owns a 64-column B-tile for ALL of K=512,
// staged once into LDS (single barrier), then a fully-unrolled barrier-free
// K-sweep; A-frags stream direct from global. AF32: A is fp32 and is cast to
// bf16 in-register (folds the x-cast kernel into the GEMM).
// EPI=1 (QKV): bf16 out, segmented bias + gamma row-scale. EPI=0: fp32+bias.
// ---------------------------------------------------------------------------
template<int MS, int EPI, bool AF32>
__global__ __launch_bounds__(256) void gemm_persistB(
    const void* __restrict__ Av, const bf16* __restrict__ Bt,
    const float* __restrict__ b0, const float* __restrict__ b1,
    const float* __restrict__ b2,
    float* __restrict__ Cf, bf16* __restrict__ Cb, int ldc)
{
    constexpr int K = 512;
    constexpr int LDB = 520;              // +8 shorts pad -> <=2-way aliasing
    constexpr int TM = MS / 64;
    __shared__ alignas(16) short Bs[64 * LDB];   // 66.5 KB -> 2 blocks/CU

    const int tid = threadIdx.x;
    const int wave = tid >> 6, lane = tid & 63;
    const int fr = lane & 15, quad = lane >> 4;
    const int n0 = blockIdx.x * 64;
    const int m0 = blockIdx.y * MS;

    // ---- stage B once: each row = 1 KB contiguous = one async16 wave-instr
    #pragma unroll
    for (int i = 0; i < 16; ++i) {
        const int row = wave * 16 + i;
        async16(&Bt[(size_t)(n0 + row) * K + lane * 8], &Bs[row * LDB]);
    }
    __syncthreads();   // single barrier; vmcnt drain folded in here

    const int arow = m0 + wave * (MS / 4) + fr;

    f32x4 acc[TM][4] = {};
    #pragma unroll
    for (int ks = 0; ks < 16; ++ks) {
        short8 bfrag[4];
        #pragma unroll
        for (int j = 0; j < 4; ++j)
            bfrag[j] = *(const short8*)&Bs[(j * 16 + fr) * LDB + ks * 32 + quad * 8];
        #pragma unroll
        for (int i = 0; i < TM; ++i) {
            short8 af;
            if (AF32) {
                const float* pa = (const float*)Av
                    + (size_t)(arow + i * 16) * K + quad * 8 + ks * 32;
                float4 u0 = *(const float4*)pa;
                float4 u1 = *(const float4*)(pa + 4);
                alignas(16) unsigned short tmp[8] = {
                    f2bf_bits(u0.x), f2bf_bits(u0.y), f2bf_bits(u0.z), f2bf_bits(u0.w),
                    f2bf_bits(u1.x), f2bf_bits(u1.y), f2bf_bits(u1.z), f2bf_bits(u1.w)};
                af = *(const short8*)tmp;
            } else {
                af = *(const short8*)((const bf16*)Av
                    + (size_t)(arow + i * 16) * K + quad * 8 + ks * 32);
            }
            #pragma unroll
            for (int j = 0; j < 4; ++j)
                acc[i][j] = __builtin_amdgcn_mfma_f32_16x16x32_bf16(
                    af, bfrag[j], acc[i][j], 0, 0, 0);
        }
    }

    // Epilogue. C/D layout: col(n)=lane&15, row(m)=quad*4+reg.
    if (EPI == 1) {
        const int seg = n0 >> 9;   // q/k/v segment (block-uniform)
        const float* bp = seg == 0 ? b0 : seg == 1 ? b1 : b2;
        const float sgn = seg == 0 ? 0.5f : seg == 1 ? -0.5f : 0.0f;
        #pragma unroll
        for (int i = 0; i < TM; ++i) {
            const int mrow = m0 + wave * (MS / 4) + i * 16 + quad * 4;
            float sc[4];
            #pragma unroll
            for (int r = 0; r < 4; ++r)
                sc[r] = exp2f((float)((mrow + r) & 63) * (sgn * LOG2_GAMMA));
            #pragma unroll
            for (int j = 0; j < 4; ++j) {
                const int n = n0 + j * 16 + fr;
                const float bv = bp[n & 511];
                #pragma unroll
                for (int r = 0; r < 4; ++r) {
                    unsigned short h = f2bf_bits((acc[i][j][r] + bv) * sc[r]);
                    *(unsigned short*)&Cb[(size_t)(mrow + r) * ldc + n] = h;
                }
            }
        }
    } else {
        #pragma unroll
        for (int i = 0; i < TM; ++i) {
            const int mrow = m0 + wave * (MS / 4) + i * 16 + quad * 4;
            #pragma unroll
            for (int j = 0; j < 4; ++j) {
                const int n = n0 + j * 16 + fr;
                const float bv = b0[n];
                #pragma unroll
                for (int r = 0; r < 4; ++r)
                    Cf[(size_t)(mrow + r) * ldc + n] = acc[i][j][r] + bv;
            }
        }
    }
}

// ---------------------------------------------------------------------------
// Single-barrier MFMA power attention. Decay row-scales pre-folded into q,k.
// Stage Q + all (<=3) K-tiles + all V^T-tiles, ONE __syncthreads, then a
// barrier-free MFMA sweep (Ps round-trip is same-wave only).
// ---------------------------------------------------------------------------
__global__ __launch_bounds__(256) void power_attn_mfma(
    const bf16* __restrict__ qkv, bf16* __restrict__ atc)
{
    __shared__ alignas(16) short Qs[64 * 32];        // 4 KB
    __shared__ alignas(16) short Ks[3][64 * 32];     // 12 KB
    __shared__ alignas(16) short Vt[3][32 * 80];     // 15 KB  [d][s], stride 80
    __shared__ alignas(16) short Ps[64 * 72];        // 9 KB   [t][s], stride 72

    const int tid = threadIdx.x, wave = tid >> 6, lane = tid & 63;
    const int chunk = blockIdx.x, bh = blockIdx.y;
    const int b = bh >> 4, h = bh & 15;
    const int mb = b * SEQ + chunk * 64;
    const int fr = lane & 15, quad = lane >> 4;
    const int jstart = chunk >= 2 ? chunk - 2 : 0;   // gamma^129 ~ 1e-6
    const int cnt = chunk - jstart + 1;              // 1..3 tiles

    // stage Q (wave w -> its own 16 rows) and all K tiles
    async16(&qkv[(size_t)(mb + wave * 16 + (lane >> 2)) * 1536 + h * 32 + (lane & 3) * 8],
            &Qs[wave * 512]);
    for (int jj = 0; jj < cnt; ++jj) {
        const int sb = b * SEQ + (jstart + jj) * 64;
        async16(&qkv[(size_t)(sb + wave * 16 + (lane >> 2)) * 1536 + 512 + h * 32 + (lane & 3) * 8],
                &Ks[jj][wave * 512]);
    }
    // transpose-stage all V tiles: cnt*128 tasks, each packs 2 s-cols x 8 dims
    #pragma unroll
    for (int u = 0; u < 2; ++u) {
        const int task = tid + u * 256;
        if (task < cnt * 128) {
            const int jj = task >> 7, tt = task & 127;
            const int s = (tt >> 2) * 2, dbase = (tt & 3) * 8;
            const int sb = b * SEQ + (jstart + jj) * 64;
            const short* g = (const short*)&qkv[(size_t)(sb + s) * 1536 + 1024 + h * 32 + dbase];
            short8 v0 = *(const short8*)g;
            short8 v1 = *(const short8*)(g + 1536);
            #pragma unroll
            for (int i = 0; i < 8; ++i) {
                unsigned pk = (unsigned)(unsigned short)v0[i]
                            | ((unsigned)(unsigned short)v1[i] << 16);
                *(unsigned*)&Vt[jj][(dbase + i) * 80 + s] = pk;
            }
        }
    }
    __syncthreads();   // the only barrier

    short8 aq = *(const short8*)&Qs[(wave * 16 + fr) * 32 + quad * 8];
    f32x4 o0 = {}, o1 = {};

    for (int jj = 0; jj < cnt; ++jj) {
        // S = Q @ K^T : per wave 16x64
        f32x4 sAcc[4] = {};
        #pragma unroll
        for (int nt = 0; nt < 4; ++nt) {
            short8 bk = *(const short8*)&Ks[jj][(nt * 16 + fr) * 32 + quad * 8];
            sAcc[nt] = __builtin_amdgcn_mfma_f32_16x16x32_bf16(aq, bk, sAcc[nt], 0, 0, 0);
        }

        const int dj = cnt - 1 - jj;                 // chunk - (jstart+jj)
        const float sj = exp2f(64.0f * (float)dj * LOG2_GAMMA);
        const int tbase = wave * 16 + quad * 4;
        #pragma unroll
        for (int nt = 0; nt < 4; ++nt) {
            const int s_l = nt * 16 + fr;
            #pragma unroll
            for (int r = 0; r < 4; ++r) {
                const int t_l = tbase + r;
                float pv = sAcc[nt][r];
                pv = pv * pv * sj;
                if (dj == 0 && s_l > t_l) pv = 0.0f;
                Ps[t_l * 72 + s_l] = (short)f2bf_bits(pv);
            }
        }
        // same-wave write->read (lgkmcnt-ordered); wave reads only its rows
        short8 a0 = *(const short8*)&Ps[(wave * 16 + fr) * 72 + quad * 8];
        short8 a1 = *(const short8*)&Ps[(wave * 16 + fr) * 72 + 32 + quad * 8];
        short8 b00 = *(const short8*)&Vt[jj][fr * 80 + quad * 8];
        short8 b01 = *(const short8*)&Vt[jj][fr * 80 + 32 + quad * 8];
        short8 b10 = *(const short8*)&Vt[jj][(16 + fr) * 80 + quad * 8];
        short8 b11 = *(const short8*)&Vt[jj][(16 + fr) * 80 + 32 + quad * 8];
        o0 = __builtin_amdgcn_mfma_f32_16x16x32_bf16(a0, b00, o0, 0, 0, 0);
        o0 = __builtin_amdgcn_mfma_f32_16x16x32_bf16(a1, b01, o0, 0, 0, 0);
        o1 = __builtin_amdgcn_mfma_f32_16x16x32_bf16(a0, b10, o1, 0, 0, 0);
        o1 = __builtin_amdgcn_mfma_f32_16x16x32_bf16(a1, b11, o1, 0, 0, 0);
    }

    #pragma unroll
    for (int r = 0; r < 4; ++r) {
        const size_t row = mb + wave * 16 + quad * 4 + r;
        const int col = h * 32 + fr;
        *(unsigned short*)&atc[row * 512 + col]      = f2bf_bits(o0[r]);
        *(unsigned short*)&atc[row * 512 + col + 16] = f2bf_bits(o1[r]);
    }
}

// ---------------------------------------------------------------------------
extern "C" void kernel_launch(void* const* d_in, const int* in_sizes, int n_in,
                              void* d_out, int out_size, void* d_ws, size_t ws_size,
                              hipStream_t stream)
{
    const float* x  = (const float*)d_in[0];
    const float* qw = (const float*)d_in[1];
    const float* qb = (const float*)d_in[2];
    const float* kw = (const float*)d_in[3];
    const float* kb = (const float*)d_in[4];
    const float* vw = (const float*)d_in[5];
    const float* vb = (const float*)d_in[6];
    const float* ow = (const float*)d_in[7];
    const float* ob = (const float*)d_in[8];
    float* out = (float*)d_out;

    char* w = (char*)d_ws;
    bf16* wqkvt = (bf16*)(w);                        // 1.5 MB [1536][512]
    bf16* wot   = (bf16*)(w + (1536ull << 10));      // 0.5 MB [512][512]
    bf16* qkvb  = (bf16*)(w + (2ull << 20));         // 6 MB   [2048][1536]
    bf16* atc   = (bf16*)(w + (8ull << 20));         // 2 MB   [2048][512]

    prep_w<<<256, 256, 0, stream>>>(qw, kw, vw, ow, wqkvt, wot);

    // QKV GEMM (x cast folded in): fp32 [2048][512] x [1536][512]^T -> bf16
    gemm_persistB<128, 1, true><<<dim3(1536 / 64, MROWS / 128), 256, 0, stream>>>(
        x, wqkvt, qb, kb, vb, nullptr, qkvb, 1536);

    power_attn_mfma<<<dim3(SEQ / 64, BATCH * NHEADS), 256, 0, stream>>>(qkvb, atc);

    // Output GEMM: bf16 [2048][512] x [512][512]^T -> fp32 out
    gemm_persistB<64, 0, false><<<dim3(512 / 64, MROWS / 64), 256, 0, stream>>>(
        atc, wot, ob, nullptr, nullptr, out, nullptr, 512);
}

// Round 7
// 99.004 us; speedup vs baseline: 1.0644x; 1.0644x over previous
//
#include <hip/hip_runtime.h>
#include <hip/hip_bf16.h>
#include <math.h>

// Problem constants
#define HIDDEN 512
#define NHEADS 16
#define HDIM   32
#define BATCH  2
#define SEQ    1024
#define MROWS  (BATCH * SEQ)   // 2048

constexpr float LOG2_GAMMA = -0.15200309344504997f; // log2(0.9)

typedef __hip_bfloat16 bf16;
typedef __attribute__((ext_vector_type(8))) short short8;
typedef __attribute__((ext_vector_type(4))) float f32x4;

__device__ __forceinline__ void async16(const void* g, void* l) {
    __builtin_amdgcn_global_load_lds(
        (const __attribute__((address_space(1))) void*)g,
        (__attribute__((address_space(3))) void*)l, 16, 0, 0);
}

__device__ __forceinline__ unsigned short f2bf_bits(float f) {
    bf16 b = __float2bfloat16(f);
    return *(unsigned short*)&b;
}

// ---------------------------------------------------------------------------
// Fused prep: blocks 0-255 transpose+cast the 4 weights (fp32 [512 k][512 n]
// -> bf16 [n][512 k]); blocks 256-511 cast x fp32 -> bf16.
// ---------------------------------------------------------------------------
__global__ __launch_bounds__(256) void prep(
    const float* __restrict__ x,
    const float* __restrict__ qw, const float* __restrict__ kw,
    const float* __restrict__ vw, const float* __restrict__ ow,
    bf16* __restrict__ xb, bf16* __restrict__ wqkvt, bf16* __restrict__ wot)
{
    const int blk = blockIdx.x, tid = threadIdx.x;
    if (blk < 256) {
        const int widx = blk >> 6;
        const int tile = blk & 63;
        const int tk = (tile & 7) * 64, tn = (tile >> 3) * 64;
        const float* w = widx == 0 ? qw : widx == 1 ? kw : widx == 2 ? vw : ow;
        __shared__ float t[64][65];
        #pragma unroll
        for (int u = 0; u < 4; ++u) {
            const int r = u * 16 + (tid >> 4);
            const int c = (tid & 15) * 4;
            float4 v = *(const float4*)&w[(size_t)(tk + r) * 512 + tn + c];
            t[r][c + 0] = v.x; t[r][c + 1] = v.y; t[r][c + 2] = v.z; t[r][c + 3] = v.w;
        }
        __syncthreads();
        #pragma unroll
        for (int u = 0; u < 2; ++u) {
            const int rr = u * 32 + (tid >> 3);
            const int cc = (tid & 7) * 8;
            alignas(16) unsigned short tmp[8];
            #pragma unroll
            for (int i = 0; i < 8; ++i) tmp[i] = f2bf_bits(t[cc + i][rr]);
            bf16* dst = (widx < 3)
                ? &wqkvt[((size_t)widx * 512 + tn + rr) * 512 + tk + cc]
                : &wot[(size_t)(tn + rr) * 512 + tk + cc];
            *(short8*)dst = *(short8*)tmp;
        }
    } else {
        #pragma unroll
        for (int u = 0; u < 4; ++u) {
            const int idx = (blk - 256) * 1024 + u * 256 + tid;
            float4 v = ((const float4*)x)[idx];
            unsigned pk0 = (unsigned)f2bf_bits(v.x) | ((unsigned)f2bf_bits(v.y) << 16);
            unsigned pk1 = (unsigned)f2bf_bits(v.z) | ((unsigned)f2bf_bits(v.w) << 16);
            uint2 pk = {pk0, pk1};
            *(uint2*)&xb[(size_t)idx * 4] = pk;
        }
    }
}

// ---------------------------------------------------------------------------
// Full-K-resident MFMA GEMM, 64x64 tile, K=512 in two BK=256 LDS stages.
// Both panels live in LDS (32 KB + 32 KB); only 3 barriers per block total.
// async16 forbids padding, so rows use an XOR chunk swizzle: 16B-chunk c of
// row r is stored at slot c^(r&7); reads XOR the byte offset with (r&7)*16.
// That caps bank aliasing at 2-way (free) instead of 16-way.
// 4 waves 2x2, wave tile 32x32. EPI=1: bf16 out + segmented bias + gamma
// row-scale (QKV). EPI=0: fp32 out + bias (out-proj).
// ---------------------------------------------------------------------------
template<int EPI>
__global__ __launch_bounds__(256) void gemm_tile64(
    const bf16* __restrict__ A, const bf16* __restrict__ Bt,
    const float* __restrict__ b0, const float* __restrict__ b1,
    const float* __restrict__ b2,
    float* __restrict__ Cf, bf16* __restrict__ Cb, int ldc)
{
    constexpr int K = 512;
    __shared__ alignas(16) short As[64 * 256];   // 32 KB, row = 256 shorts
    __shared__ alignas(16) short Bs[64 * 256];   // 32 KB

    const int tid = threadIdx.x;
    const int wave = tid >> 6, lane = tid & 63;
    const int fr = lane & 15, quad = lane >> 4;
    const int m0 = blockIdx.y * 64, n0 = blockIdx.x * 64;
    const int wm = (wave >> 1) * 32, wn = (wave & 1) * 32;

    const int rl = lane >> 5;    // staging: row within the 2-row wave-instr
    const int chs = lane & 31;   // staging: chunk slot within row

    // fragment read bases (XOR-swizzled)
    const int ar0 = wm + fr, ar1 = ar0 + 16;
    const int br0 = wn + fr, br1 = br0 + 16;
    const char* cA0 = (const char*)&As[ar0 * 256];
    const char* cA1 = (const char*)&As[ar1 * 256];
    const char* cB0 = (const char*)&Bs[br0 * 256];
    const char* cB1 = (const char*)&Bs[br1 * 256];
    const int xa0 = (ar0 & 7) * 16, xa1 = (ar1 & 7) * 16;
    const int xb0 = (br0 & 7) * 16, xb1 = (br1 & 7) * 16;

    f32x4 acc[2][2] = {};

    #pragma unroll
    for (int kk = 0; kk < 2; ++kk) {
        if (kk) __syncthreads();   // previous stage's readers done
        #pragma unroll
        for (int j = 0; j < 8; ++j) {
            const int r0 = wave * 16 + j * 2;      // 2 rows per wave-instr
            const int row = r0 + rl;
            const int g = chs ^ (row & 7);         // fetch swizzled chunk
            async16(&A[(size_t)(m0 + row) * K + kk * 256 + g * 8], &As[r0 * 256]);
            async16(&Bt[(size_t)(n0 + row) * K + kk * 256 + g * 8], &Bs[r0 * 256]);
        }
        __syncthreads();   // vmcnt drain + barrier

        #pragma unroll
        for (int ks = 0; ks < 8; ++ks) {
            const int cb = (ks * 4 + quad) * 16;   // byte offset pre-swizzle
            short8 a0 = *(const short8*)(cA0 + (cb ^ xa0));
            short8 a1 = *(const short8*)(cA1 + (cb ^ xa1));
            short8 q0 = *(const short8*)(cB0 + (cb ^ xb0));
            short8 q1 = *(const short8*)(cB1 + (cb ^ xb1));
            acc[0][0] = __builtin_amdgcn_mfma_f32_16x16x32_bf16(a0, q0, acc[0][0], 0, 0, 0);
            acc[0][1] = __builtin_amdgcn_mfma_f32_16x16x32_bf16(a0, q1, acc[0][1], 0, 0, 0);
            acc[1][0] = __builtin_amdgcn_mfma_f32_16x16x32_bf16(a1, q0, acc[1][0], 0, 0, 0);
            acc[1][1] = __builtin_amdgcn_mfma_f32_16x16x32_bf16(a1, q1, acc[1][1], 0, 0, 0);
        }
    }

    // Epilogue. C/D layout: col(n)=lane&15, row(m)=quad*4+reg.
    if (EPI == 1) {
        const int seg = n0 >> 9;   // q/k/v segment (block-uniform)
        const float* bp = seg == 0 ? b0 : seg == 1 ? b1 : b2;
        const float sgn = seg == 0 ? 0.5f : seg == 1 ? -0.5f : 0.0f;
        #pragma unroll
        for (int i = 0; i < 2; ++i) {
            const int mrow = m0 + wm + i * 16 + quad * 4;
            float sc[4];
            #pragma unroll
            for (int r = 0; r < 4; ++r)
                sc[r] = exp2f((float)((mrow + r) & 63) * (sgn * LOG2_GAMMA));
            #pragma unroll
            for (int j = 0; j < 2; ++j) {
                const int n = n0 + wn + j * 16 + fr;
                const float bv = bp[n & 511];
                #pragma unroll
                for (int r = 0; r < 4; ++r) {
                    unsigned short hh = f2bf_bits((acc[i][j][r] + bv) * sc[r]);
                    *(unsigned short*)&Cb[(size_t)(mrow + r) * ldc + n] = hh;
                }
            }
        }
    } else {
        #pragma unroll
        for (int i = 0; i < 2; ++i) {
            const int mrow = m0 + wm + i * 16 + quad * 4;
            #pragma unroll
            for (int j = 0; j < 2; ++j) {
                const int n = n0 + wn + j * 16 + fr;
                const float bv = b0[n];
                #pragma unroll
                for (int r = 0; r < 4; ++r)
                    Cf[(size_t)(mrow + r) * ldc + n] = acc[i][j][r] + bv;
            }
        }
    }
}

// ---------------------------------------------------------------------------
// Single-barrier MFMA power attention. Decay row-scales pre-folded into q,k.
// Q loads straight into A-layout registers; K-tiles async-staged with the
// XOR swizzle (chunks-per-row=4); V^T staged transposed. One __syncthreads,
// then a barrier-free MFMA sweep (Ps round-trip is same-wave only).
// ---------------------------------------------------------------------------
__global__ __launch_bounds__(256) void power_attn_mfma(
    const bf16* __restrict__ qkv, bf16* __restrict__ atc)
{
    __shared__ alignas(16) short Ks[3][64 * 32];     // 12 KB (XOR-swizzled)
    __shared__ alignas(16) short Vt[3][32 * 80];     // 15 KB  [d][s], stride 80
    __shared__ alignas(16) short Ps[64 * 72];        // 9 KB   [t][s], stride 72

    const int tid = threadIdx.x, wave = tid >> 6, lane = tid & 63;
    const int chunk = blockIdx.x, bh = blockIdx.y;
    const int b = bh >> 4, h = bh & 15;
    const int mb = b * SEQ + chunk * 64;
    const int fr = lane & 15, quad = lane >> 4;
    const int jstart = chunk >= 2 ? chunk - 2 : 0;   // gamma^129 ~ 1e-6
    const int cnt = chunk - jstart + 1;              // 1..3 tiles

    // Q fragment direct from global (A-layout: m=fr, k=quad*8+j)
    short8 aq = *(const short8*)&qkv[(size_t)(mb + wave * 16 + fr) * 1536 + h * 32 + quad * 8];

    // stage K tiles (XOR swizzle: row r chunk c -> slot c^(r&3))
    const int srow = lane >> 2;                      // row within 16-row group
    const int sg = (lane & 3) ^ (srow & 3);          // swizzled fetch chunk
    for (int jj = 0; jj < cnt; ++jj) {
        const int sb = b * SEQ + (jstart + jj) * 64;
        async16(&qkv[(size_t)(sb + wave * 16 + srow) * 1536 + 512 + h * 32 + sg * 8],
                &Ks[jj][wave * 512]);
    }
    // transpose-stage all V tiles: cnt*128 tasks, each packs 2 s-cols x 8 dims
    #pragma unroll
    for (int u = 0; u < 2; ++u) {
        const int task = tid + u * 256;
        if (task < cnt * 128) {
            const int jj = task >> 7, tt = task & 127;
            const int s = (tt >> 2) * 2, dbase = (tt & 3) * 8;
            const int sb = b * SEQ + (jstart + jj) * 64;
            const short* g = (const short*)&qkv[(size_t)(sb + s) * 1536 + 1024 + h * 32 + dbase];
            short8 v0 = *(const short8*)g;
            short8 v1 = *(const short8*)(g + 1536);
            #pragma unroll
            for (int i = 0; i < 8; ++i) {
                unsigned pk = (unsigned)(unsigned short)v0[i]
                            | ((unsigned)(unsigned short)v1[i] << 16);
                *(unsigned*)&Vt[jj][(dbase + i) * 80 + s] = pk;
            }
        }
    }
    __syncthreads();   // the only barrier

    f32x4 o0 = {}, o1 = {};

    for (int jj = 0; jj < cnt; ++jj) {
        // S = Q @ K^T : per wave 16x64; K-frag reads undo the XOR swizzle
        f32x4 sAcc[4] = {};
        #pragma unroll
        for (int nt = 0; nt < 4; ++nt) {
            const int krow = nt * 16 + fr;
            short8 bk = *(const short8*)((const char*)&Ks[jj][0]
                          + krow * 64 + ((quad * 16) ^ ((fr & 3) * 16)));
            sAcc[nt] = __builtin_amdgcn_mfma_f32_16x16x32_bf16(aq, bk, sAcc[nt], 0, 0, 0);
        }

        const int dj = cnt - 1 - jj;                 // chunk - (jstart+jj)
        const float sj = exp2f(64.0f * (float)dj * LOG2_GAMMA);
        const int tbase = wave * 16 + quad * 4;
        #pragma unroll
        for (int nt = 0; nt < 4; ++nt) {
            const int s_l = nt * 16 + fr;
            #pragma unroll
            for (int r = 0; r < 4; ++r) {
                const int t_l = tbase + r;
                float pv = sAcc[nt][r];
                pv = pv * pv * sj;
                if (dj == 0 && s_l > t_l) pv = 0.0f;
                Ps[t_l * 72 + s_l] = (short)f2bf_bits(pv);
            }
        }
        // same-wave write->read (lgkmcnt-ordered); wave reads only its rows
        short8 a0 = *(const short8*)&Ps[(wave * 16 + fr) * 72 + quad * 8];
        short8 a1 = *(const short8*)&Ps[(wave * 16 + fr) * 72 + 32 + quad * 8];
        short8 b00 = *(const short8*)&Vt[jj][fr * 80 + quad * 8];
        short8 b01 = *(const short8*)&Vt[jj][fr * 80 + 32 + quad * 8];
        short8 b10 = *(const short8*)&Vt[jj][(16 + fr) * 80 + quad * 8];
        short8 b11 = *(const short8*)&Vt[jj][(16 + fr) * 80 + 32 + quad * 8];
        o0 = __builtin_amdgcn_mfma_f32_16x16x32_bf16(a0, b00, o0, 0, 0, 0);
        o0 = __builtin_amdgcn_mfma_f32_16x16x32_bf16(a1, b01, o0, 0, 0, 0);
        o1 = __builtin_amdgcn_mfma_f32_16x16x32_bf16(a0, b10, o1, 0, 0, 0);
        o1 = __builtin_amdgcn_mfma_f32_16x16x32_bf16(a1, b11, o1, 0, 0, 0);
    }

    #pragma unroll
    for (int r = 0; r < 4; ++r) {
        const size_t row = mb + wave * 16 + quad * 4 + r;
        const int col = h * 32 + fr;
        *(unsigned short*)&atc[row * 512 + col]      = f2bf_bits(o0[r]);
        *(unsigned short*)&atc[row * 512 + col + 16] = f2bf_bits(o1[r]);
    }
}

// ---------------------------------------------------------------------------
extern "C" void kernel_launch(void* const* d_in, const int* in_sizes, int n_in,
                              void* d_out, int out_size, void* d_ws, size_t ws_size,
                              hipStream_t stream)
{
    const float* x  = (const float*)d_in[0];
    const float* qw = (const float*)d_in[1];
    const float* qb = (const float*)d_in[2];
    const float* kw = (const float*)d_in[3];
    const float* kb = (const float*)d_in[4];
    const float* vw = (const float*)d_in[5];
    const float* vb = (const float*)d_in[6];
    const float* ow = (const float*)d_in[7];
    const float* ob = (const float*)d_in[8];
    float* out = (float*)d_out;

    char* w = (char*)d_ws;
    bf16* xb    = (bf16*)(w);                                    // 2 MB   [2048][512]
    bf16* wqkvt = (bf16*)(w + (2ull  << 20));                    // 1.5 MB [1536][512]
    bf16* wot   = (bf16*)(w + (2ull  << 20) + (1536ull << 10));  // 0.5 MB [512][512]
    bf16* qkvb  = (bf16*)(w + (4ull  << 20));                    // 6 MB   [2048][1536]
    bf16* atc   = (bf16*)(w + (10ull << 20));                    // 2 MB   [2048][512]

    prep<<<512, 256, 0, stream>>>(x, qw, kw, vw, ow, xb, wqkvt, wot);

    // QKV GEMM: bf16 [2048][512] x [1536][512]^T -> bf16 [2048][1536] (scaled)
    gemm_tile64<1><<<dim3(1536 / 64, MROWS / 64), 256, 0, stream>>>(
        xb, wqkvt, qb, kb, vb, nullptr, qkvb, 1536);

    power_attn_mfma<<<dim3(SEQ / 64, BATCH * NHEADS), 256, 0, stream>>>(qkvb, atc);

    // Output GEMM: bf16 [2048][512] x [512][512]^T -> fp32 out
    gemm_tile64<0><<<dim3(512 / 64, MROWS / 64), 256, 0, stream>>>(
        atc, wot, ob, nullptr, nullptr, out, nullptr, 512);
}